// Round 3
// baseline (590.043 us; speedup 1.0000x reference)
//
#include <hip/hip_runtime.h>
#include <hip/hip_fp16.h>
#include <math.h>

#define N_NODES 100000
#define N_EDGES 1600000
#define HDIM    128
#define NCLS    10
#define NGRAPH  1000
#define GEMM_BLOCKS  ((N_NODES + 127) / 128)   // 782
// radix-bucket CSR build
#define BSHIFT   9
#define BUCKW    (1 << BSHIFT)                 // 512 nodes / bucket
#define NB       ((N_NODES + BUCKW - 1) >> BSHIFT)   // 196
#define EPB      4096                          // edges per chunk block
#define NCHUNKS  ((N_EDGES + EPB - 1) / EPB)   // 391
#define SWZ_BLOCKS 24                          // 6144 threads / 256
#define PREP_BLOCKS NCHUNKS                    // 391; 2*391 == GEMM_BLOCKS
#define SMEM_BYTES 35376                       // scatter phase is the max

typedef _Float16 half8 __attribute__((ext_vector_type(8)));
typedef float    f32x4 __attribute__((ext_vector_type(4)));

static __device__ __forceinline__ float elu1(float x) {
  return x > 0.f ? x : (__expf(x) - 1.f);
}

// async 16B global->LDS (m97 pattern; literal size arg)
static __device__ __forceinline__ void gload_lds16(const void* g, void* l) {
  __builtin_amdgcn_global_load_lds(
      (const __attribute__((address_space(1))) unsigned int*)g,
      (__attribute__((address_space(3))) unsigned int*)l, 16, 0, 0);
}

// ---------- device-scope grid barrier (all blocks resident by construction)
// Canonical leader-spin barrier: release-fence + arrive, acquire-spin,
// fence, block barrier. bar[] zeroed by hipMemsetAsync before launch.
static __device__ __forceinline__ void gbar(int* bar, int idx, int nb) {
  __syncthreads();
  if (threadIdx.x == 0) {
    __threadfence();                              // device-scope release
    atomicAdd(&bar[idx], 1);                      // device-scope RMW (m20)
    while (__hip_atomic_load(&bar[idx], __ATOMIC_ACQUIRE,
                             __HIP_MEMORY_SCOPE_AGENT) < nb) {
      __builtin_amdgcn_s_sleep(2);
    }
    __threadfence();
  }
  __syncthreads();
}

// ---------- MFMA GEMM: Ch[n,128](fp16) = A[n,128] @ Wswz ----------
// v_mfma_f32_16x16x32_f16; block = 4 waves x 32 rows. Layouts (m89/m120):
// A[m=lane&15][k=quad*8+j], D col=lane&15 row=quad*4+reg.
template <bool AHALF, bool STAGE>
__device__ __forceinline__
void gemm_mfma_body(const void* __restrict__ Av, const half8* __restrict__ Wswz,
                    __half* __restrict__ Ch, int nrows, half8* WtF, int bid) {
  int tid = threadIdx.x;
  int wv = tid >> 6, lane = tid & 63;
  int quad = lane >> 4, l15 = lane & 15;
  int m0 = bid * 128 + wv * 32;
  int r0 = m0 + l15;      if (r0 > nrows - 1) r0 = nrows - 1;  // clamp; stores guarded
  int r1 = m0 + 16 + l15; if (r1 > nrows - 1) r1 = nrows - 1;

  // ---- A prefetch into registers (issues before staging) ----
  half8 ah[2][4];
  float4 af[2][4][2];
  if constexpr (AHALF) {
    const __half* Ah = (const __half*)Av;
#pragma unroll
    for (int k0 = 0; k0 < 4; ++k0) {
      ah[0][k0] = *(const half8*)(Ah + (size_t)r0 * 128 + k0 * 32 + quad * 8);
      ah[1][k0] = *(const half8*)(Ah + (size_t)r1 * 128 + k0 * 32 + quad * 8);
    }
  } else {
    const float* Af = (const float*)Av;
#pragma unroll
    for (int k0 = 0; k0 < 4; ++k0) {
      const float* p0 = Af + (size_t)r0 * 128 + k0 * 32 + quad * 8;
      const float* p1 = Af + (size_t)r1 * 128 + k0 * 32 + quad * 8;
      af[0][k0][0] = *(const float4*)p0; af[0][k0][1] = *(const float4*)(p0 + 4);
      af[1][k0][0] = *(const float4*)p1; af[1][k0][1] = *(const float4*)(p1 + 4);
    }
  }

  // ---- async W staging (32KB, linear lane-consecutive -> gload_lds safe) ----
  if constexpr (STAGE) {
    for (int i = tid; i < 2048; i += 256) gload_lds16(Wswz + i, WtF + i);
  }
  __syncthreads();   // drains vmcnt (A prefetch + staging) before LDS reads

  f32x4 acc[2][8];
#pragma unroll
  for (int mt = 0; mt < 2; ++mt)
#pragma unroll
    for (int nt = 0; nt < 8; ++nt) acc[mt][nt] = (f32x4){0.f, 0.f, 0.f, 0.f};

#pragma unroll
  for (int k0 = 0; k0 < 4; ++k0) {
    half8 a0, a1;
    if constexpr (AHALF) {
      a0 = ah[0][k0];
      a1 = ah[1][k0];
    } else {
      float4 x0 = af[0][k0][0], y0 = af[0][k0][1];
      float4 x1 = af[1][k0][0], y1 = af[1][k0][1];
      a0[0] = (_Float16)x0.x; a0[1] = (_Float16)x0.y;
      a0[2] = (_Float16)x0.z; a0[3] = (_Float16)x0.w;
      a0[4] = (_Float16)y0.x; a0[5] = (_Float16)y0.y;
      a0[6] = (_Float16)y0.z; a0[7] = (_Float16)y0.w;
      a1[0] = (_Float16)x1.x; a1[1] = (_Float16)x1.y;
      a1[2] = (_Float16)x1.z; a1[3] = (_Float16)x1.w;
      a1[4] = (_Float16)y1.x; a1[5] = (_Float16)y1.y;
      a1[6] = (_Float16)y1.z; a1[7] = (_Float16)y1.w;
    }
#pragma unroll
    for (int nt = 0; nt < 8; ++nt) {
      half8 b = WtF[(k0 * 8 + nt) * 64 + lane];
      acc[0][nt] = __builtin_amdgcn_mfma_f32_16x16x32_f16(a0, b, acc[0][nt], 0, 0, 0);
      acc[1][nt] = __builtin_amdgcn_mfma_f32_16x16x32_f16(a1, b, acc[1][nt], 0, 0, 0);
    }
  }

#pragma unroll
  for (int mt = 0; mt < 2; ++mt) {
#pragma unroll
    for (int r = 0; r < 4; ++r) {
      int row = m0 + mt * 16 + quad * 4 + r;
      if (row < nrows) {
#pragma unroll
        for (int nt = 0; nt < 8; ++nt) {
          Ch[(size_t)row * 128 + nt * 16 + l15] = __float2half(acc[mt][nt][r]);
        }
      }
    }
  }
}

__global__ __launch_bounds__(256)
void gemm_mfma_h(const __half* __restrict__ A, const half8* __restrict__ Wswz,
                 __half* __restrict__ Ch, int nrows) {
  __shared__ half8 WtF[2048];  // 32 KB
  gemm_mfma_body<true, true>(A, Wswz, Ch, nrows, WtF, blockIdx.x);
}

// ---------- bucket_scatter body ----------
__device__ __forceinline__
void scatter_body(const int* __restrict__ ei, const int* __restrict__ cbc,
                  const int* __restrict__ cpre, const int* __restrict__ bbase,
                  int2* __restrict__ ebuf, int c,
                  int* lb, int* lcur, int* s, int2* stage) {
  int t = threadIdx.x;

  // local exclusive scan of this chunk's bucket counts
  int v = (t < NB) ? cbc[c * NB + t] : 0;
  s[t] = v;
  __syncthreads();
#pragma unroll
  for (int d = 1; d < 256; d <<= 1) {
    int val = (t >= d) ? s[t - d] : 0;
    __syncthreads();
    s[t] += val;
    __syncthreads();
  }
  if (t < NB) {
    int excl = s[t] - v;
    lb[t] = excl;
    lcur[t] = excl;
  }
  if (t == 255) lb[NB] = s[255];  // edges in this chunk
  __syncthreads();

  // scatter into LDS (bucket-grouped)
#pragma unroll
  for (int k = 0; k < EPB / 256; ++k) {
    int e = c * EPB + k * 256 + t;
    if (e < N_EDGES) {
      int src = ei[e];
      int d = ei[N_EDGES + e];
      int p = atomicAdd(&lcur[d >> BSHIFT], 1);
      stage[p] = make_int2(src, d);
    }
  }
  __syncthreads();

  // coalesced flush: wave w handles buckets w, w+4, ...
  int wv = t >> 6, lane = t & 63;
  for (int b = wv; b < NB; b += 4) {
    int l0 = lb[b], l1 = lb[b + 1];
    int gb = bbase[b] + cpre[c * NB + b];
    for (int i = lane; i < l1 - l0; i += 64) ebuf[gb + i] = stage[l0 + i];
  }
}

// ---------- bucket_csr body (hist + scan -> off/dinv + dst-sorted csrc) ---
__device__ __forceinline__
void csr_body(const int2* __restrict__ ebuf, const int* __restrict__ bbase,
              int* __restrict__ off, float* __restrict__ dinv,
              int* __restrict__ csrc, int b, int* hist, int* cur, int* s) {
  int t = threadIdx.x;
  int node0 = b << BSHIFT;
  int ebeg = bbase[b], eend = bbase[b + 1];

  hist[t] = 0; hist[t + 256] = 0;
  __syncthreads();
  for (int e = ebeg + t; e < eend; e += 256)
    atomicAdd(&hist[ebuf[e].y - node0], 1);
  __syncthreads();

  int a = hist[2 * t], bq = hist[2 * t + 1];
  int sum = a + bq;
  s[t] = sum;
  __syncthreads();
#pragma unroll
  for (int d = 1; d < 256; d <<= 1) {
    int val = (t >= d) ? s[t - d] : 0;
    __syncthreads();
    s[t] += val;
    __syncthreads();
  }
  int run = s[t] - sum;
  cur[2 * t] = run;
  cur[2 * t + 1] = run + a;

  int i0 = node0 + 2 * t, i1 = node0 + 2 * t + 1;
  if (i0 < N_NODES) {
    off[i0] = ebeg + run;
    dinv[i0] = rsqrtf((float)(a + 1));
  }
  if (i1 < N_NODES) {
    off[i1] = ebeg + run + a;
    dinv[i1] = rsqrtf((float)(bq + 1));
  }
  if (b == NB - 1 && t == 0) off[N_NODES] = N_EDGES;
  __syncthreads();

  for (int e = ebeg + t; e < eend; e += 256) {
    int2 ed = ebuf[e];
    int p = atomicAdd(&cur[ed.y - node0], 1);
    csrc[ebeg + p] = ed.x;
  }
}

// ---------- PERSISTENT PREP: everything before the first aggregate --------
// R14: one 391-block all-resident kernel with device-scope grid barriers.
// P0: bucket_count(bid) + gbound slice + W swizzle (bid<24)
// P1: scan_chunks (bid<196)   P2: scan_base (bid 0)
// P3: scatter (all)           P4: csr (bid<196) || gemm0 (2 tiles/block)
// Replaces 5 launches + their device-wide drain points; overlaps the
// latency-bound 196-block csr with gemm0 tiles.
// Residency proof: __launch_bounds__(256,2) -> >=2 blocks/CU = 512 >= 391;
// LDS 35.4KB -> 4 blocks/CU. All blocks resident; no early returns.
__global__ __launch_bounds__(256, 2)
void prep(const float* __restrict__ W0, const float* __restrict__ W1,
          const float* __restrict__ W2, half8* __restrict__ Wswz,
          const int* __restrict__ ei, const int* __restrict__ batch,
          int* __restrict__ goff, int* __restrict__ cbc,
          int* __restrict__ cpre, int* __restrict__ btot,
          int* __restrict__ bbase, int2* __restrict__ ebuf,
          int* __restrict__ off, float* __restrict__ dinv,
          int* __restrict__ csrc, const float* __restrict__ x,
          __half* __restrict__ hbuf, int* __restrict__ bar) {
  __shared__ __align__(16) char smem[SMEM_BYTES];
  int bid = blockIdx.x;
  int t = threadIdx.x;

  // ---- P0a: per-chunk dst-bucket histogram (chunk = bid) ----
  {
    int* hist = (int*)smem;
    if (t < NB) hist[t] = 0;
    __syncthreads();
#pragma unroll
    for (int k = 0; k < EPB / 256; ++k) {
      int e = bid * EPB + k * 256 + t;
      if (e < N_EDGES) atomicAdd(&hist[ei[N_EDGES + e] >> BSHIFT], 1);
    }
    __syncthreads();
    if (t < NB) cbc[bid * NB + t] = hist[t];
  }
  // ---- P0b: graph bounds from sorted batch (no LDS) ----
  {
    int i = bid * 256 + t;
    if (i < N_NODES) {
      int b = batch[i];
      if (i == 0) {
        for (int g = 0; g <= b; ++g) goff[g] = 0;
      } else {
        int a = batch[i - 1];
        for (int g = a + 1; g <= b; ++g) goff[g] = i;
      }
      if (i == N_NODES - 1) {
        for (int g = b + 1; g <= NGRAPH; ++g) goff[g] = N_NODES;
      }
    }
  }
  // ---- P0c: W swizzle f32[128][128] -> fp16 B-fragment order (m89) ----
  if (bid < SWZ_BLOCKS) {
    int f = bid * 256 + t;            // 0..6143
    int which = f >> 11;
    const float* W = (which == 0) ? W0 : ((which == 1) ? W1 : W2);
    int r = f & 2047;
    int frag = r >> 6;                // k0*8+nt
    int lane = r & 63;
    int k0 = frag >> 3, nt = frag & 7;
    int n = nt * 16 + (lane & 15);
    int kbase = k0 * 32 + (lane >> 4) * 8;
    half8 hb;
#pragma unroll
    for (int j = 0; j < 8; ++j) hb[j] = (_Float16)W[(kbase + j) * 128 + n];
    Wswz[f] = hb;
  }
  gbar(bar, 0, PREP_BLOCKS);

  // ---- P1: per-bucket exclusive scan along chunk axis (bid<NB) ----
  if (bid < NB) {
    int* s = (int*)smem;
    int c0 = 2 * t, c1 = 2 * t + 1;
    int v0 = (c0 < NCHUNKS) ? cbc[c0 * NB + bid] : 0;
    int v1 = (c1 < NCHUNKS) ? cbc[c1 * NB + bid] : 0;
    int sum = v0 + v1;
    s[t] = sum;
    __syncthreads();
#pragma unroll
    for (int d = 1; d < 256; d <<= 1) {
      int val = (t >= d) ? s[t - d] : 0;
      __syncthreads();
      s[t] += val;
      __syncthreads();
    }
    int run = s[t] - sum;
    if (c0 < NCHUNKS) cpre[c0 * NB + bid] = run;
    if (c1 < NCHUNKS) cpre[c1 * NB + bid] = run + v0;
    if (t == 255) btot[bid] = s[255];
  }
  gbar(bar, 1, PREP_BLOCKS);

  // ---- P2: exclusive scan over bucket totals (block 0) ----
  if (bid == 0) {
    int* s = (int*)smem;
    int v = (t < NB) ? btot[t] : 0;
    s[t] = v;
    __syncthreads();
#pragma unroll
    for (int d = 1; d < 256; d <<= 1) {
      int val = (t >= d) ? s[t - d] : 0;
      __syncthreads();
      s[t] += val;
      __syncthreads();
    }
    if (t < NB) bbase[t] = s[t] - v;
    if (t == 255) bbase[NB] = s[255];  // == N_EDGES
  }
  gbar(bar, 2, PREP_BLOCKS);

  // ---- P3: LDS-staged coalesced scatter (chunk = bid) ----
  {
    int* lb = (int*)smem;            // 197
    int* lcur = lb + (NB + 1);       // 196
    int* ss = lcur + NB;             // 256
    int2* stage = (int2*)(smem + 2608);  // 4096 x 8B
    scatter_body(ei, cbc, cpre, bbase, ebuf, bid, lb, lcur, ss, stage);
  }
  gbar(bar, 3, PREP_BLOCKS);

  // ---- P4: csr finalize (bid<NB) overlapped with layer-0 GEMM tiles ----
  if (bid < NB) {
    int* hist = (int*)smem;          // 512
    int* cur = hist + BUCKW;         // 512
    int* s = cur + BUCKW;            // 256
    csr_body(ebuf, bbase, off, dinv, csrc, bid, hist, cur, s);
    __syncthreads();                 // LDS reuse: cs -> WtF
  }
  half8* WtF = (half8*)smem;
  gemm_mfma_body<false, true>(x, Wswz, hbuf, N_NODES, WtF, bid);
  __syncthreads();                   // all WtF reads done before... (same data; cheap guard)
  gemm_mfma_body<false, false>(x, Wswz, hbuf, N_NODES, WtF, bid + PREP_BLOCKS);
}

// ---------- gather-accumulate one node row (lane holds 2 features) --------
static __device__ __forceinline__
float2 gather_row(const __half2* __restrict__ h2, const int* __restrict__ csrc,
                  const float* __restrict__ dinv, int node, int lane,
                  int beg, int end) {
  float a0 = 0.f, a1 = 0.f;
  float b0_ = 0.f, b1_ = 0.f;
  float c0 = 0.f, c1 = 0.f;
  float d0 = 0.f, d1 = 0.f;

  int e = beg;
  for (; e + 8 <= end; e += 8) {
    int s0 = csrc[e + 0], s1 = csrc[e + 1], s2 = csrc[e + 2], s3 = csrc[e + 3];
    int s4 = csrc[e + 4], s5 = csrc[e + 5], s6 = csrc[e + 6], s7 = csrc[e + 7];
    float w0 = dinv[s0], w1 = dinv[s1], w2 = dinv[s2], w3 = dinv[s3];
    float w4 = dinv[s4], w5 = dinv[s5], w6 = dinv[s6], w7 = dinv[s7];
    float2 f0 = __half22float2(h2[(size_t)s0 * 64 + lane]);
    float2 f1 = __half22float2(h2[(size_t)s1 * 64 + lane]);
    float2 f2 = __half22float2(h2[(size_t)s2 * 64 + lane]);
    float2 f3 = __half22float2(h2[(size_t)s3 * 64 + lane]);
    float2 f4 = __half22float2(h2[(size_t)s4 * 64 + lane]);
    float2 f5 = __half22float2(h2[(size_t)s5 * 64 + lane]);
    float2 f6 = __half22float2(h2[(size_t)s6 * 64 + lane]);
    float2 f7 = __half22float2(h2[(size_t)s7 * 64 + lane]);
    a0 = fmaf(w0, f0.x, a0); a1 = fmaf(w0, f0.y, a1);
    b0_ = fmaf(w1, f1.x, b0_); b1_ = fmaf(w1, f1.y, b1_);
    c0 = fmaf(w2, f2.x, c0); c1 = fmaf(w2, f2.y, c1);
    d0 = fmaf(w3, f3.x, d0); d1 = fmaf(w3, f3.y, d1);
    a0 = fmaf(w4, f4.x, a0); a1 = fmaf(w4, f4.y, a1);
    b0_ = fmaf(w5, f5.x, b0_); b1_ = fmaf(w5, f5.y, b1_);
    c0 = fmaf(w6, f6.x, c0); c1 = fmaf(w6, f6.y, c1);
    d0 = fmaf(w7, f7.x, d0); d1 = fmaf(w7, f7.y, d1);
  }
  if (e + 4 <= end) {
    int s0 = csrc[e + 0], s1 = csrc[e + 1], s2 = csrc[e + 2], s3 = csrc[e + 3];
    float w0 = dinv[s0], w1 = dinv[s1], w2 = dinv[s2], w3 = dinv[s3];
    float2 f0 = __half22float2(h2[(size_t)s0 * 64 + lane]);
    float2 f1 = __half22float2(h2[(size_t)s1 * 64 + lane]);
    float2 f2 = __half22float2(h2[(size_t)s2 * 64 + lane]);
    float2 f3 = __half22float2(h2[(size_t)s3 * 64 + lane]);
    a0 = fmaf(w0, f0.x, a0); a1 = fmaf(w0, f0.y, a1);
    b0_ = fmaf(w1, f1.x, b0_); b1_ = fmaf(w1, f1.y, b1_);
    c0 = fmaf(w2, f2.x, c0); c1 = fmaf(w2, f2.y, c1);
    d0 = fmaf(w3, f3.x, d0); d1 = fmaf(w3, f3.y, d1);
    e += 4;
  }
  if (e + 2 <= end) {
    int s0 = csrc[e + 0], s1 = csrc[e + 1];
    float w0 = dinv[s0], w1 = dinv[s1];
    float2 f0 = __half22float2(h2[(size_t)s0 * 64 + lane]);
    float2 f1 = __half22float2(h2[(size_t)s1 * 64 + lane]);
    a0 = fmaf(w0, f0.x, a0); a1 = fmaf(w0, f0.y, a1);
    b0_ = fmaf(w1, f1.x, b0_); b1_ = fmaf(w1, f1.y, b1_);
    e += 2;
  }
  if (e < end) {
    int s0 = csrc[e];
    float w0 = dinv[s0];
    float2 f0 = __half22float2(h2[(size_t)s0 * 64 + lane]);
    a0 = fmaf(w0, f0.x, a0); a1 = fmaf(w0, f0.y, a1);
  }

  float dv = dinv[node];
  float2 vs = __half22float2(h2[(size_t)node * 64 + lane]);
  float2 r;
  r.x = ((a0 + b0_) + (c0 + d0) + dv * vs.x) * dv;
  r.y = ((a1 + b1_) + (c1 + d1) + dv * vs.y) * dv;
  return r;
}

// ---------- aggregation (R1's proven 62.4us shape: wave/node, scalar path)
__global__ __launch_bounds__(256)
void aggregate(const __half* __restrict__ h, const int* __restrict__ off,
               const int* __restrict__ csrc, const float* __restrict__ dinv,
               const float* __restrict__ bias, __half* __restrict__ out) {
  int gid = blockIdx.x * blockDim.x + threadIdx.x;
  int node = __builtin_amdgcn_readfirstlane(gid >> 6);   // wave-uniform
  int lane = threadIdx.x & 63;
  if (node >= N_NODES) return;
  const __half2* h2 = (const __half2*)h;

  int beg = off[node], end = off[node + 1];
  float2 sacc = gather_row(h2, csrc, dinv, node, lane, beg, end);
  float2 bb = ((const float2*)bias)[lane];
  float ox = elu1(sacc.x + bb.x);
  float oy = elu1(sacc.y + bb.y);
  ((__half2*)out)[(size_t)node * 64 + lane] = __floats2half2_rn(ox, oy);
}

// ---------- fused max-pool + linear head + softmax ----------
__global__ __launch_bounds__(256)
void pool_head(const __half* __restrict__ feat, const int* __restrict__ goff,
               const float* __restrict__ Wl, const float* __restrict__ bl,
               float* __restrict__ out) {
  int g = blockIdx.x;
  int t = threadIdx.x;          // 0..255
  int f = t & 127, hh = t >> 7;
  int beg = goff[g], end = goff[g + 1];

  float m0 = -INFINITY, m1 = -INFINITY, m2 = -INFINITY, m3 = -INFINITY;
  int i = beg + hh;
  for (; i + 6 < end; i += 8) {
    m0 = fmaxf(m0, __half2float(feat[(size_t)(i + 0) * HDIM + f]));
    m1 = fmaxf(m1, __half2float(feat[(size_t)(i + 2) * HDIM + f]));
    m2 = fmaxf(m2, __half2float(feat[(size_t)(i + 4) * HDIM + f]));
    m3 = fmaxf(m3, __half2float(feat[(size_t)(i + 6) * HDIM + f]));
  }
  for (; i < end; i += 2) m0 = fmaxf(m0, __half2float(feat[(size_t)i * HDIM + f]));
  float m = fmaxf(fmaxf(m0, m1), fmaxf(m2, m3));

  __shared__ float pl[2][HDIM];
  __shared__ float lg[NCLS];
  pl[hh][f] = m;
  __syncthreads();

  if (t < HDIM) {
    float mm = fmaxf(pl[0][t], pl[1][t]);
    if (beg == end) mm = 0.f;
    pl[0][t] = mm;
  }
  __syncthreads();

  if (t < NCLS) {
    float acc = bl[t];
#pragma unroll
    for (int ff = 0; ff < HDIM; ++ff) acc = fmaf(pl[0][ff], Wl[ff * NCLS + t], acc);
    lg[t] = acc;
  }
  __syncthreads();

  if (t < NCLS) {
    float mx = lg[0];
#pragma unroll
    for (int c = 1; c < NCLS; ++c) mx = fmaxf(mx, lg[c]);
    float ssum = 0.f;
#pragma unroll
    for (int c = 0; c < NCLS; ++c) ssum += __expf(lg[c] - mx);
    out[g * NCLS + t] = __expf(lg[t] - mx) / ssum;
  }
}

// ---------- launch ----------

extern "C" void kernel_launch(void* const* d_in, const int* in_sizes, int n_in,
                              void* d_out, int out_size, void* d_ws, size_t ws_size,
                              hipStream_t stream) {
  const float* x    = (const float*)d_in[0];
  const int*   ei   = (const int*)d_in[1];
  const int*   batch= (const int*)d_in[2];
  const float* W0 = (const float*)d_in[3]; const float* b0 = (const float*)d_in[4];
  const float* W1 = (const float*)d_in[5]; const float* b1 = (const float*)d_in[6];
  const float* W2 = (const float*)d_in[7]; const float* b2 = (const float*)d_in[8];
  const float* Wl = (const float*)d_in[9]; const float* bl = (const float*)d_in[10];
  float* out = (float*)d_out;

  char* w = (char*)d_ws;
  auto alloc = [&](size_t bytes) {
    char* p = w;
    w += (bytes + 255) & ~(size_t)255;
    return p;
  };
  int*    bar    = (int*)   alloc(64);
  int*    cbc    = (int*)   alloc((size_t)NCHUNKS * NB * 4);
  int*    cpre   = (int*)   alloc((size_t)NCHUNKS * NB * 4);
  int*    btot   = (int*)   alloc((size_t)NB * 4);
  int*    bbase  = (int*)   alloc((size_t)(NB + 1) * 4);
  int2*   ebuf   = (int2*)  alloc((size_t)N_EDGES * 8);
  int*    off    = (int*)   alloc((size_t)(N_NODES + 1) * 4);
  float*  dinv   = (float*) alloc((size_t)N_NODES * 4);
  int*    goff   = (int*)   alloc((size_t)(NGRAPH + 1) * 4);
  int*    csrc   = (int*)   alloc((size_t)N_EDGES * 4);
  half8*  Wswz   = (half8*) alloc((size_t)3 * 2048 * 16);
  __half* hbuf   = (__half*)alloc((size_t)N_NODES * HDIM * 2);
  __half* feat   = (__half*)alloc((size_t)N_NODES * HDIM * 2);

  // zero grid-barrier counters (stream-ordered, graph-capturable)
  hipMemsetAsync(bar, 0, 64, stream);

  // one persistent kernel: count+gbound+swizzle | scans | scatter | csr||gemm0
  prep<<<PREP_BLOCKS, 256, 0, stream>>>(
      W0, W1, W2, Wswz, ei, batch, goff, cbc, cpre, btot, bbase,
      ebuf, off, dinv, csrc, x, hbuf, bar);

  aggregate<<<((size_t)N_NODES * 64 + 255) / 256, 256, 0, stream>>>(
      hbuf, off, csrc, dinv, b0, feat);

  gemm_mfma_h<<<GEMM_BLOCKS, 256, 0, stream>>>(feat, Wswz + 2048, hbuf, N_NODES);
  aggregate<<<((size_t)N_NODES * 64 + 255) / 256, 256, 0, stream>>>(
      hbuf, off, csrc, dinv, b1, feat);

  gemm_mfma_h<<<GEMM_BLOCKS, 256, 0, stream>>>(feat, Wswz + 4096, hbuf, N_NODES);
  aggregate<<<((size_t)N_NODES * 64 + 255) / 256, 256, 0, stream>>>(
      hbuf, off, csrc, dinv, b2, feat);

  pool_head<<<NGRAPH, 256, 0, stream>>>(feat, goff, Wl, bl, out);
}

// Round 4
// 390.419 us; speedup vs baseline: 1.5113x; 1.5113x over previous
//
#include <hip/hip_runtime.h>
#include <hip/hip_fp16.h>
#include <math.h>

#define N_NODES 100000
#define N_EDGES 1600000
#define HDIM    128
#define NCLS    10
#define NGRAPH  1000
#define GEMM_BLOCKS  ((N_NODES + 127) / 128)   // 782
// radix-bucket CSR build
#define BSHIFT   9
#define BUCKW    (1 << BSHIFT)                 // 512 nodes / bucket
#define NB       ((N_NODES + BUCKW - 1) >> BSHIFT)   // 196
#define EPB      4096                          // edges per chunk block
#define NCHUNKS  ((N_EDGES + EPB - 1) / EPB)   // 391
#define SWZ_BLOCKS 24                          // 6144 threads / 256
#define GB_BLOCKS  ((N_NODES + 255) / 256)     // 391

typedef _Float16 half8 __attribute__((ext_vector_type(8)));
typedef float    f32x4 __attribute__((ext_vector_type(4)));

static __device__ __forceinline__ float elu1(float x) {
  return x > 0.f ? x : (__expf(x) - 1.f);
}

// async 16B global->LDS (m97 pattern; literal size arg)
static __device__ __forceinline__ void gload_lds16(const void* g, void* l) {
  __builtin_amdgcn_global_load_lds(
      (const __attribute__((address_space(1))) unsigned int*)g,
      (__attribute__((address_space(3))) unsigned int*)l, 16, 0, 0);
}

// ---------- MFMA GEMM: Ch[n,128](fp16) = A[n,128] @ Wswz ----------
// v_mfma_f32_16x16x32_f16; block = 4 waves x 32 rows. Layouts (m89/m120):
// A[m=lane&15][k=quad*8+j], D col=lane&15 row=quad*4+reg.
template <bool AHALF>
__device__ __forceinline__
void gemm_mfma_body(const void* __restrict__ Av, const half8* __restrict__ Wswz,
                    __half* __restrict__ Ch, int nrows, half8* WtF, int bid) {
  int tid = threadIdx.x;
  int wv = tid >> 6, lane = tid & 63;
  int quad = lane >> 4, l15 = lane & 15;
  int m0 = bid * 128 + wv * 32;
  int r0 = m0 + l15;      if (r0 > nrows - 1) r0 = nrows - 1;  // clamp; stores guarded
  int r1 = m0 + 16 + l15; if (r1 > nrows - 1) r1 = nrows - 1;

  // ---- A prefetch into registers (issues before staging) ----
  half8 ah[2][4];
  float4 af[2][4][2];
  if constexpr (AHALF) {
    const __half* Ah = (const __half*)Av;
#pragma unroll
    for (int k0 = 0; k0 < 4; ++k0) {
      ah[0][k0] = *(const half8*)(Ah + (size_t)r0 * 128 + k0 * 32 + quad * 8);
      ah[1][k0] = *(const half8*)(Ah + (size_t)r1 * 128 + k0 * 32 + quad * 8);
    }
  } else {
    const float* Af = (const float*)Av;
#pragma unroll
    for (int k0 = 0; k0 < 4; ++k0) {
      const float* p0 = Af + (size_t)r0 * 128 + k0 * 32 + quad * 8;
      const float* p1 = Af + (size_t)r1 * 128 + k0 * 32 + quad * 8;
      af[0][k0][0] = *(const float4*)p0; af[0][k0][1] = *(const float4*)(p0 + 4);
      af[1][k0][0] = *(const float4*)p1; af[1][k0][1] = *(const float4*)(p1 + 4);
    }
  }

  // ---- async W staging (32KB, linear lane-consecutive -> gload_lds safe) ----
  for (int i = tid; i < 2048; i += 256) gload_lds16(Wswz + i, WtF + i);
  __syncthreads();   // drains vmcnt (A prefetch + staging) before LDS reads

  f32x4 acc[2][8];
#pragma unroll
  for (int mt = 0; mt < 2; ++mt)
#pragma unroll
    for (int nt = 0; nt < 8; ++nt) acc[mt][nt] = (f32x4){0.f, 0.f, 0.f, 0.f};

#pragma unroll
  for (int k0 = 0; k0 < 4; ++k0) {
    half8 a0, a1;
    if constexpr (AHALF) {
      a0 = ah[0][k0];
      a1 = ah[1][k0];
    } else {
      float4 x0 = af[0][k0][0], y0 = af[0][k0][1];
      float4 x1 = af[1][k0][0], y1 = af[1][k0][1];
      a0[0] = (_Float16)x0.x; a0[1] = (_Float16)x0.y;
      a0[2] = (_Float16)x0.z; a0[3] = (_Float16)x0.w;
      a0[4] = (_Float16)y0.x; a0[5] = (_Float16)y0.y;
      a0[6] = (_Float16)y0.z; a0[7] = (_Float16)y0.w;
      a1[0] = (_Float16)x1.x; a1[1] = (_Float16)x1.y;
      a1[2] = (_Float16)x1.z; a1[3] = (_Float16)x1.w;
      a1[4] = (_Float16)y1.x; a1[5] = (_Float16)y1.y;
      a1[6] = (_Float16)y1.z; a1[7] = (_Float16)y1.w;
    }
#pragma unroll
    for (int nt = 0; nt < 8; ++nt) {
      half8 b = WtF[(k0 * 8 + nt) * 64 + lane];
      acc[0][nt] = __builtin_amdgcn_mfma_f32_16x16x32_f16(a0, b, acc[0][nt], 0, 0, 0);
      acc[1][nt] = __builtin_amdgcn_mfma_f32_16x16x32_f16(a1, b, acc[1][nt], 0, 0, 0);
    }
  }

#pragma unroll
  for (int mt = 0; mt < 2; ++mt) {
#pragma unroll
    for (int r = 0; r < 4; ++r) {
      int row = m0 + mt * 16 + quad * 4 + r;
      if (row < nrows) {
#pragma unroll
        for (int nt = 0; nt < 8; ++nt) {
          Ch[(size_t)row * 128 + nt * 16 + l15] = __float2half(acc[mt][nt][r]);
        }
      }
    }
  }
}

__global__ __launch_bounds__(256)
void gemm_mfma_h(const __half* __restrict__ A, const half8* __restrict__ Wswz,
                 __half* __restrict__ Ch, int nrows) {
  __shared__ half8 WtF[2048];  // 32 KB
  gemm_mfma_body<true>(A, Wswz, Ch, nrows, WtF, blockIdx.x);
}

// ---------- bucket_scatter body ----------
__device__ __forceinline__
void scatter_body(const int* __restrict__ ei, const int* __restrict__ cbc,
                  const int* __restrict__ cpre, const int* __restrict__ bbase,
                  int2* __restrict__ ebuf, int c,
                  int* lb, int* lcur, int* s, int2* stage) {
  int t = threadIdx.x;

  // local exclusive scan of this chunk's bucket counts
  int v = (t < NB) ? cbc[c * NB + t] : 0;
  s[t] = v;
  __syncthreads();
#pragma unroll
  for (int d = 1; d < 256; d <<= 1) {
    int val = (t >= d) ? s[t - d] : 0;
    __syncthreads();
    s[t] += val;
    __syncthreads();
  }
  if (t < NB) {
    int excl = s[t] - v;
    lb[t] = excl;
    lcur[t] = excl;
  }
  if (t == 255) lb[NB] = s[255];  // edges in this chunk
  __syncthreads();

  // scatter into LDS (bucket-grouped)
#pragma unroll
  for (int k = 0; k < EPB / 256; ++k) {
    int e = c * EPB + k * 256 + t;
    if (e < N_EDGES) {
      int src = ei[e];
      int d = ei[N_EDGES + e];
      int p = atomicAdd(&lcur[d >> BSHIFT], 1);
      stage[p] = make_int2(src, d);
    }
  }
  __syncthreads();

  // coalesced flush: wave w handles buckets w, w+4, ...
  int wv = t >> 6, lane = t & 63;
  for (int b = wv; b < NB; b += 4) {
    int l0 = lb[b], l1 = lb[b + 1];
    int gb = bbase[b] + cpre[c * NB + b];
    for (int i = lane; i < l1 - l0; i += 64) ebuf[gb + i] = stage[l0 + i];
  }
}

// ---------- MERGED front-end #1: swizzle_w || bucket_count || gbound ------
__global__ __launch_bounds__(256)
void front1(const float* __restrict__ W0, const float* __restrict__ W1,
            const float* __restrict__ W2, half8* __restrict__ Wswz,
            const int* __restrict__ ei, int* __restrict__ cbc,
            const int* __restrict__ batch, int* __restrict__ goff) {
  int bid = blockIdx.x;
  int t = threadIdx.x;
  if (bid < SWZ_BLOCKS) {
    // ---- W swizzle: f32 [128][128] -> fp16 B-fragment order (m89) ----
    int f = bid * 256 + t;            // 0..6143
    int which = f >> 11;
    const float* W = (which == 0) ? W0 : ((which == 1) ? W1 : W2);
    int r = f & 2047;
    int frag = r >> 6;                // k0*8+nt
    int lane = r & 63;
    int k0 = frag >> 3, nt = frag & 7;
    int n = nt * 16 + (lane & 15);
    int kbase = k0 * 32 + (lane >> 4) * 8;
    half8 hb;
#pragma unroll
    for (int j = 0; j < 8; ++j) hb[j] = (_Float16)W[(kbase + j) * 128 + n];
    Wswz[f] = hb;
  } else if (bid < SWZ_BLOCKS + NCHUNKS) {
    // ---- per-chunk histogram over 196 buckets ----
    __shared__ int hist[NB];
    int c = bid - SWZ_BLOCKS;
    if (t < NB) hist[t] = 0;
    __syncthreads();
#pragma unroll
    for (int k = 0; k < EPB / 256; ++k) {
      int e = c * EPB + k * 256 + t;
      if (e < N_EDGES) atomicAdd(&hist[ei[N_EDGES + e] >> BSHIFT], 1);
    }
    __syncthreads();
    if (t < NB) cbc[c * NB + t] = hist[t];
  } else {
    // ---- graph (pooling) ranges from SORTED batch ----
    int i = (bid - SWZ_BLOCKS - NCHUNKS) * 256 + t;
    if (i >= N_NODES) return;
    int b = batch[i];
    if (i == 0) {
      for (int g = 0; g <= b; ++g) goff[g] = 0;
    } else {
      int a = batch[i - 1];
      for (int g = a + 1; g <= b; ++g) goff[g] = i;
    }
    if (i == N_NODES - 1) {
      for (int g = b + 1; g <= NGRAPH; ++g) goff[g] = N_NODES;
    }
  }
}

// ---------- MERGED mid: layer-0 GEMM (fp32 A) || bucket_scatter -----------
// R1's proven pairing: 1173 blocks, union'd LDS, true overlap.
__global__ __launch_bounds__(256)
void mid2(const float* __restrict__ x, const half8* __restrict__ Wswz,
          __half* __restrict__ hbuf,
          const int* __restrict__ ei, const int* __restrict__ cbc,
          const int* __restrict__ cpre, const int* __restrict__ bbase,
          int2* __restrict__ ebuf) {
  __shared__ union {
    half8 WtF[2048];                                    // 32 KB (gemm path)
    struct { int lb[NB + 1]; int lcur[NB]; int s[256]; int2 stage[EPB]; } sc;
  } u;
  int bid = blockIdx.x;
  if (bid < GEMM_BLOCKS) {
    gemm_mfma_body<false>(x, Wswz, hbuf, N_NODES, u.WtF, bid);
  } else {
    scatter_body(ei, cbc, cpre, bbase, ebuf, bid - GEMM_BLOCKS,
                 u.sc.lb, u.sc.lcur, u.sc.s, u.sc.stage);
  }
}

// B1: per-bucket exclusive scan along the chunk axis (parallel over buckets)
__global__ __launch_bounds__(256)
void scan_chunks(const int* __restrict__ cbc, int* __restrict__ cpre,
                 int* __restrict__ btot) {
  __shared__ int s[256];
  int b = blockIdx.x;
  int t = threadIdx.x;
  int c0 = 2 * t, c1 = 2 * t + 1;
  int v0 = (c0 < NCHUNKS) ? cbc[c0 * NB + b] : 0;
  int v1 = (c1 < NCHUNKS) ? cbc[c1 * NB + b] : 0;
  int sum = v0 + v1;
  s[t] = sum;
  __syncthreads();
#pragma unroll
  for (int d = 1; d < 256; d <<= 1) {
    int val = (t >= d) ? s[t - d] : 0;
    __syncthreads();
    s[t] += val;
    __syncthreads();
  }
  int run = s[t] - sum;
  if (c0 < NCHUNKS) cpre[c0 * NB + b] = run;
  if (c1 < NCHUNKS) cpre[c1 * NB + b] = run + v0;
  if (t == 255) btot[b] = s[255];
}

// B2: exclusive scan over bucket totals -> bbase[b], bbase[NB] = E
__global__ __launch_bounds__(256)
void scan_base(const int* __restrict__ btot, int* __restrict__ bbase) {
  __shared__ int s[256];
  int t = threadIdx.x;
  int v = (t < NB) ? btot[t] : 0;
  s[t] = v;
  __syncthreads();
#pragma unroll
  for (int d = 1; d < 256; d <<= 1) {
    int val = (t >= d) ? s[t - d] : 0;
    __syncthreads();
    s[t] += val;
    __syncthreads();
  }
  if (t < NB) bbase[t] = s[t] - v;
  if (t == 255) bbase[NB] = s[255];  // == N_EDGES
}

// D: one block per bucket: LDS 512-histogram + local scan -> off, dinv,
// and dst-sorted csrc.
__global__ __launch_bounds__(256)
void bucket_csr(const int2* __restrict__ ebuf, const int* __restrict__ bbase,
                int* __restrict__ off, float* __restrict__ dinv,
                int* __restrict__ csrc) {
  __shared__ int hist[BUCKW];
  __shared__ int cur[BUCKW];
  __shared__ int s[256];
  int t = threadIdx.x;
  int b = blockIdx.x;
  int node0 = b << BSHIFT;
  int ebeg = bbase[b], eend = bbase[b + 1];

  hist[t] = 0; hist[t + 256] = 0;
  __syncthreads();
  for (int e = ebeg + t; e < eend; e += 256)
    atomicAdd(&hist[ebuf[e].y - node0], 1);
  __syncthreads();

  int a = hist[2 * t], bq = hist[2 * t + 1];
  int sum = a + bq;
  s[t] = sum;
  __syncthreads();
#pragma unroll
  for (int d = 1; d < 256; d <<= 1) {
    int val = (t >= d) ? s[t - d] : 0;
    __syncthreads();
    s[t] += val;
    __syncthreads();
  }
  int run = s[t] - sum;
  cur[2 * t] = run;
  cur[2 * t + 1] = run + a;

  int i0 = node0 + 2 * t, i1 = node0 + 2 * t + 1;
  if (i0 < N_NODES) {
    off[i0] = ebeg + run;
    dinv[i0] = rsqrtf((float)(a + 1));
  }
  if (i1 < N_NODES) {
    off[i1] = ebeg + run + a;
    dinv[i1] = rsqrtf((float)(bq + 1));
  }
  if (b == NB - 1 && t == 0) off[N_NODES] = N_EDGES;
  __syncthreads();

  for (int e = ebeg + t; e < eend; e += 256) {
    int2 ed = ebuf[e];
    int p = atomicAdd(&cur[ed.y - node0], 1);
    csrc[ebeg + p] = ed.x;
  }
}

// ---------- aggregation: TWO nodes per wave, temporally interleaved -------
// R15: R1's counters showed no saturated pipe (HBM 51% of achievable, L2
// far below ceiling, VALU 24%) -> latency-bound. Two wave-uniform nodes
// give two independent scalar chains (csrc->dinv) + 8 vector loads in
// flight, while keeping the scalar-path + full-row coalescing of R1.
#define STEP4(EE, P0, P1, Q0, Q1, R0, R1, S0, S1)                            \
  {                                                                          \
    int s0 = csrc[EE + 0], s1 = csrc[EE + 1];                                \
    int s2 = csrc[EE + 2], s3 = csrc[EE + 3];                                \
    float w0 = dinv[s0], w1 = dinv[s1], w2 = dinv[s2], w3 = dinv[s3];        \
    float2 f0 = __half22float2(h2[(size_t)s0 * 64 + lane]);                  \
    float2 f1 = __half22float2(h2[(size_t)s1 * 64 + lane]);                  \
    float2 f2 = __half22float2(h2[(size_t)s2 * 64 + lane]);                  \
    float2 f3 = __half22float2(h2[(size_t)s3 * 64 + lane]);                  \
    P0 = fmaf(w0, f0.x, P0); P1 = fmaf(w0, f0.y, P1);                        \
    Q0 = fmaf(w1, f1.x, Q0); Q1 = fmaf(w1, f1.y, Q1);                        \
    R0 = fmaf(w2, f2.x, R0); R1 = fmaf(w2, f2.y, R1);                        \
    S0 = fmaf(w3, f3.x, S0); S1 = fmaf(w3, f3.y, S1);                        \
  }

#define STEP1(EE, P0, P1)                                                    \
  {                                                                          \
    int s0 = csrc[EE];                                                       \
    float w0 = dinv[s0];                                                     \
    float2 f0 = __half22float2(h2[(size_t)s0 * 64 + lane]);                  \
    P0 = fmaf(w0, f0.x, P0); P1 = fmaf(w0, f0.y, P1);                        \
  }

__global__ __launch_bounds__(256)
void aggregate(const __half* __restrict__ h, const int* __restrict__ off,
               const int* __restrict__ csrc, const float* __restrict__ dinv,
               const float* __restrict__ bias, __half* __restrict__ out) {
  int gid = blockIdx.x * blockDim.x + threadIdx.x;
  int wid = __builtin_amdgcn_readfirstlane(gid >> 6);    // wave-uniform
  int lane = threadIdx.x & 63;
  int nodeA = wid * 2;
  if (nodeA >= N_NODES) return;
  int nodeB = nodeA + 1;                                 // N_NODES is even
  const __half2* h2 = (const __half2*)h;

  int begA = off[nodeA], endA = off[nodeA + 1];
  int begB = endA, endB = off[nodeB + 1];                // CSR contiguity

  float aA0 = 0.f, aA1 = 0.f, bA0 = 0.f, bA1 = 0.f;
  float cA0 = 0.f, cA1 = 0.f, dA0 = 0.f, dA1 = 0.f;
  float aB0 = 0.f, aB1 = 0.f, bB0 = 0.f, bB1 = 0.f;
  float cB0 = 0.f, cB1 = 0.f, dB0 = 0.f, dB1 = 0.f;

  int eA = begA, eB = begB;
  while (eA + 4 <= endA && eB + 4 <= endB) {
    STEP4(eA, aA0, aA1, bA0, bA1, cA0, cA1, dA0, dA1);
    STEP4(eB, aB0, aB1, bB0, bB1, cB0, cB1, dB0, dB1);
    eA += 4; eB += 4;
  }
  while (eA + 4 <= endA) {
    STEP4(eA, aA0, aA1, bA0, bA1, cA0, cA1, dA0, dA1);
    eA += 4;
  }
  while (eB + 4 <= endB) {
    STEP4(eB, aB0, aB1, bB0, bB1, cB0, cB1, dB0, dB1);
    eB += 4;
  }
  for (; eA < endA; ++eA) STEP1(eA, aA0, aA1);
  for (; eB < endB; ++eB) STEP1(eB, aB0, aB1);

  float2 bb = ((const float2*)bias)[lane];

  float dvA = dinv[nodeA];
  float2 vsA = __half22float2(h2[(size_t)nodeA * 64 + lane]);
  float sA0 = ((aA0 + bA0) + (cA0 + dA0) + dvA * vsA.x) * dvA;
  float sA1 = ((aA1 + bA1) + (cA1 + dA1) + dvA * vsA.y) * dvA;
  ((__half2*)out)[(size_t)nodeA * 64 + lane] =
      __floats2half2_rn(elu1(sA0 + bb.x), elu1(sA1 + bb.y));

  float dvB = dinv[nodeB];
  float2 vsB = __half22float2(h2[(size_t)nodeB * 64 + lane]);
  float sB0 = ((aB0 + bB0) + (cB0 + dB0) + dvB * vsB.x) * dvB;
  float sB1 = ((aB1 + bB1) + (cB1 + dB1) + dvB * vsB.y) * dvB;
  ((__half2*)out)[(size_t)nodeB * 64 + lane] =
      __floats2half2_rn(elu1(sB0 + bb.x), elu1(sB1 + bb.y));
}

// ---------- fused max-pool + linear head + softmax ----------
__global__ __launch_bounds__(256)
void pool_head(const __half* __restrict__ feat, const int* __restrict__ goff,
               const float* __restrict__ Wl, const float* __restrict__ bl,
               float* __restrict__ out) {
  int g = blockIdx.x;
  int t = threadIdx.x;          // 0..255
  int f = t & 127, hh = t >> 7;
  int beg = goff[g], end = goff[g + 1];

  float m0 = -INFINITY, m1 = -INFINITY, m2 = -INFINITY, m3 = -INFINITY;
  int i = beg + hh;
  for (; i + 6 < end; i += 8) {
    m0 = fmaxf(m0, __half2float(feat[(size_t)(i + 0) * HDIM + f]));
    m1 = fmaxf(m1, __half2float(feat[(size_t)(i + 2) * HDIM + f]));
    m2 = fmaxf(m2, __half2float(feat[(size_t)(i + 4) * HDIM + f]));
    m3 = fmaxf(m3, __half2float(feat[(size_t)(i + 6) * HDIM + f]));
  }
  for (; i < end; i += 2) m0 = fmaxf(m0, __half2float(feat[(size_t)i * HDIM + f]));
  float m = fmaxf(fmaxf(m0, m1), fmaxf(m2, m3));

  __shared__ float pl[2][HDIM];
  __shared__ float lg[NCLS];
  pl[hh][f] = m;
  __syncthreads();

  if (t < HDIM) {
    float mm = fmaxf(pl[0][t], pl[1][t]);
    if (beg == end) mm = 0.f;
    pl[0][t] = mm;
  }
  __syncthreads();

  if (t < NCLS) {
    float acc = bl[t];
#pragma unroll
    for (int ff = 0; ff < HDIM; ++ff) acc = fmaf(pl[0][ff], Wl[ff * NCLS + t], acc);
    lg[t] = acc;
  }
  __syncthreads();

  if (t < NCLS) {
    float mx = lg[0];
#pragma unroll
    for (int c = 1; c < NCLS; ++c) mx = fmaxf(mx, lg[c]);
    float ssum = 0.f;
#pragma unroll
    for (int c = 0; c < NCLS; ++c) ssum += __expf(lg[c] - mx);
    out[g * NCLS + t] = __expf(lg[t] - mx) / ssum;
  }
}

// ---------- launch ----------

extern "C" void kernel_launch(void* const* d_in, const int* in_sizes, int n_in,
                              void* d_out, int out_size, void* d_ws, size_t ws_size,
                              hipStream_t stream) {
  const float* x    = (const float*)d_in[0];
  const int*   ei   = (const int*)d_in[1];
  const int*   batch= (const int*)d_in[2];
  const float* W0 = (const float*)d_in[3]; const float* b0 = (const float*)d_in[4];
  const float* W1 = (const float*)d_in[5]; const float* b1 = (const float*)d_in[6];
  const float* W2 = (const float*)d_in[7]; const float* b2 = (const float*)d_in[8];
  const float* Wl = (const float*)d_in[9]; const float* bl = (const float*)d_in[10];
  float* out = (float*)d_out;

  char* w = (char*)d_ws;
  auto alloc = [&](size_t bytes) {
    char* p = w;
    w += (bytes + 255) & ~(size_t)255;
    return p;
  };
  int*    cbc    = (int*)   alloc((size_t)NCHUNKS * NB * 4);
  int*    cpre   = (int*)   alloc((size_t)NCHUNKS * NB * 4);
  int*    btot   = (int*)   alloc((size_t)NB * 4);
  int*    bbase  = (int*)   alloc((size_t)(NB + 1) * 4);
  int2*   ebuf   = (int2*)  alloc((size_t)N_EDGES * 8);
  int*    off    = (int*)   alloc((size_t)(N_NODES + 1) * 4);
  float*  dinv   = (float*) alloc((size_t)N_NODES * 4);
  int*    goff   = (int*)   alloc((size_t)(NGRAPH + 1) * 4);
  int*    csrc   = (int*)   alloc((size_t)N_EDGES * 4);
  half8*  Wswz   = (half8*) alloc((size_t)3 * 2048 * 16);
  __half* hbufA  = (__half*)alloc((size_t)N_NODES * HDIM * 2);
  __half* feat   = (__half*)alloc((size_t)N_NODES * HDIM * 2);

  // merged front-end: W swizzle || per-chunk bucket histogram || graph bounds
  front1<<<SWZ_BLOCKS + NCHUNKS + GB_BLOCKS, 256, 0, stream>>>(
      W0, W1, W2, Wswz, ei, cbc, batch, goff);

  // scan chain (dependent, tiny)
  scan_chunks<<<NB, 256, 0, stream>>>(cbc, cpre, btot);
  scan_base<<<1, 256, 0, stream>>>(btot, bbase);

  // layer-0 GEMM runs concurrently with the edge scatter
  mid2<<<GEMM_BLOCKS + NCHUNKS, 256, 0, stream>>>(
      x, Wswz, hbufA, ei, cbc, cpre, bbase, ebuf);

  bucket_csr<<<NB, 256, 0, stream>>>(ebuf, bbase, off, dinv, csrc);

  // two nodes per wave -> half the waves, double the per-wave MLP
  const int AGG_BLOCKS = (N_NODES / 2 * 64) / 256;   // 12500
  aggregate<<<AGG_BLOCKS, 256, 0, stream>>>(hbufA, off, csrc, dinv, b0, feat);

  gemm_mfma_h<<<GEMM_BLOCKS, 256, 0, stream>>>(feat, Wswz + 2048, hbufA, N_NODES);
  aggregate<<<AGG_BLOCKS, 256, 0, stream>>>(hbufA, off, csrc, dinv, b1, feat);

  gemm_mfma_h<<<GEMM_BLOCKS, 256, 0, stream>>>(feat, Wswz + 4096, hbufA, N_NODES);
  aggregate<<<AGG_BLOCKS, 256, 0, stream>>>(hbufA, off, csrc, dinv, b2, feat);

  pool_head<<<NGRAPH, 256, 0, stream>>>(feat, goff, Wl, bl, out);
}

// Round 5
// 382.700 us; speedup vs baseline: 1.5418x; 1.0202x over previous
//
#include <hip/hip_runtime.h>
#include <hip/hip_fp16.h>
#include <math.h>

#define N_NODES 100000
#define N_EDGES 1600000
#define HDIM    128
#define NCLS    10
#define NGRAPH  1000
#define GEMM_BLOCKS  ((N_NODES + 127) / 128)   // 782
// radix-bucket CSR build
#define BSHIFT   9
#define BUCKW    (1 << BSHIFT)                 // 512 nodes / bucket
#define NB       ((N_NODES + BUCKW - 1) >> BSHIFT)   // 196
#define EPB      4096                          // edges per chunk block
#define NCHUNKS  ((N_EDGES + EPB - 1) / EPB)   // 391
#define SWZ_BLOCKS 24                          // 6144 threads / 256
#define GB_BLOCKS  ((N_NODES + 255) / 256)     // 391

typedef _Float16 half8 __attribute__((ext_vector_type(8)));
typedef float    f32x4 __attribute__((ext_vector_type(4)));

static __device__ __forceinline__ float elu1(float x) {
  return x > 0.f ? x : (__expf(x) - 1.f);
}

// async 16B global->LDS (m97 pattern; literal size arg)
static __device__ __forceinline__ void gload_lds16(const void* g, void* l) {
  __builtin_amdgcn_global_load_lds(
      (const __attribute__((address_space(1))) unsigned int*)g,
      (__attribute__((address_space(3))) unsigned int*)l, 16, 0, 0);
}

// ---------- MFMA GEMM: Ch[n,128](fp16) = A[n,128] @ Wswz ----------
// v_mfma_f32_16x16x32_f16; block = 4 waves x 32 rows. Layouts (m89/m120):
// A[m=lane&15][k=quad*8+j], D col=lane&15 row=quad*4+reg.
// R16: PRESCALE epilogue multiplies row r by dinv[r] -> output is
// h'[r] = dinv[r]*H[r], which removes the per-edge dinv chain from the
// downstream aggregate (PRE form).
template <bool AHALF, bool PRESCALE>
__device__ __forceinline__
void gemm_mfma_body(const void* __restrict__ Av, const half8* __restrict__ Wswz,
                    __half* __restrict__ Ch, int nrows, half8* WtF, int bid,
                    const float* __restrict__ dinv) {
  int tid = threadIdx.x;
  int wv = tid >> 6, lane = tid & 63;
  int quad = lane >> 4, l15 = lane & 15;
  int m0 = bid * 128 + wv * 32;
  int r0 = m0 + l15;      if (r0 > nrows - 1) r0 = nrows - 1;  // clamp; stores guarded
  int r1 = m0 + 16 + l15; if (r1 > nrows - 1) r1 = nrows - 1;

  // ---- A prefetch into registers (issues before staging) ----
  half8 ah[2][4];
  float4 af[2][4][2];
  if constexpr (AHALF) {
    const __half* Ah = (const __half*)Av;
#pragma unroll
    for (int k0 = 0; k0 < 4; ++k0) {
      ah[0][k0] = *(const half8*)(Ah + (size_t)r0 * 128 + k0 * 32 + quad * 8);
      ah[1][k0] = *(const half8*)(Ah + (size_t)r1 * 128 + k0 * 32 + quad * 8);
    }
  } else {
    const float* Af = (const float*)Av;
#pragma unroll
    for (int k0 = 0; k0 < 4; ++k0) {
      const float* p0 = Af + (size_t)r0 * 128 + k0 * 32 + quad * 8;
      const float* p1 = Af + (size_t)r1 * 128 + k0 * 32 + quad * 8;
      af[0][k0][0] = *(const float4*)p0; af[0][k0][1] = *(const float4*)(p0 + 4);
      af[1][k0][0] = *(const float4*)p1; af[1][k0][1] = *(const float4*)(p1 + 4);
    }
  }

  // ---- async W staging (32KB, linear lane-consecutive -> gload_lds safe) ----
  for (int i = tid; i < 2048; i += 256) gload_lds16(Wswz + i, WtF + i);
  __syncthreads();   // drains vmcnt (A prefetch + staging) before LDS reads

  f32x4 acc[2][8];
#pragma unroll
  for (int mt = 0; mt < 2; ++mt)
#pragma unroll
    for (int nt = 0; nt < 8; ++nt) acc[mt][nt] = (f32x4){0.f, 0.f, 0.f, 0.f};

#pragma unroll
  for (int k0 = 0; k0 < 4; ++k0) {
    half8 a0, a1;
    if constexpr (AHALF) {
      a0 = ah[0][k0];
      a1 = ah[1][k0];
    } else {
      float4 x0 = af[0][k0][0], y0 = af[0][k0][1];
      float4 x1 = af[1][k0][0], y1 = af[1][k0][1];
      a0[0] = (_Float16)x0.x; a0[1] = (_Float16)x0.y;
      a0[2] = (_Float16)x0.z; a0[3] = (_Float16)x0.w;
      a0[4] = (_Float16)y0.x; a0[5] = (_Float16)y0.y;
      a0[6] = (_Float16)y0.z; a0[7] = (_Float16)y0.w;
      a1[0] = (_Float16)x1.x; a1[1] = (_Float16)x1.y;
      a1[2] = (_Float16)x1.z; a1[3] = (_Float16)x1.w;
      a1[4] = (_Float16)y1.x; a1[5] = (_Float16)y1.y;
      a1[6] = (_Float16)y1.z; a1[7] = (_Float16)y1.w;
    }
#pragma unroll
    for (int nt = 0; nt < 8; ++nt) {
      half8 b = WtF[(k0 * 8 + nt) * 64 + lane];
      acc[0][nt] = __builtin_amdgcn_mfma_f32_16x16x32_f16(a0, b, acc[0][nt], 0, 0, 0);
      acc[1][nt] = __builtin_amdgcn_mfma_f32_16x16x32_f16(a1, b, acc[1][nt], 0, 0, 0);
    }
  }

#pragma unroll
  for (int mt = 0; mt < 2; ++mt) {
    float4 dv4 = make_float4(1.f, 1.f, 1.f, 1.f);
    if constexpr (PRESCALE) {
      int rb = m0 + mt * 16 + quad * 4;   // multiple of 4; whole quad in/out
      if (rb >= N_NODES) rb = 0;          // rows unstored anyway
      dv4 = *(const float4*)&dinv[rb];
    }
    const float* dvp = (const float*)&dv4;
#pragma unroll
    for (int r = 0; r < 4; ++r) {
      int row = m0 + mt * 16 + quad * 4 + r;
      if (row < nrows) {
#pragma unroll
        for (int nt = 0; nt < 8; ++nt) {
          float v = acc[mt][nt][r];
          if constexpr (PRESCALE) v *= dvp[r];
          Ch[(size_t)row * 128 + nt * 16 + l15] = __float2half(v);
        }
      }
    }
  }
}

__global__ __launch_bounds__(256)
void gemm_mfma_h(const __half* __restrict__ A, const half8* __restrict__ Wswz,
                 __half* __restrict__ Ch, int nrows,
                 const float* __restrict__ dinv) {
  __shared__ half8 WtF[2048];  // 32 KB
  gemm_mfma_body<true, true>(A, Wswz, Ch, nrows, WtF, blockIdx.x, dinv);
}

// ---------- bucket_scatter body ----------
__device__ __forceinline__
void scatter_body(const int* __restrict__ ei, const int* __restrict__ cbc,
                  const int* __restrict__ cpre, const int* __restrict__ bbase,
                  int2* __restrict__ ebuf, int c,
                  int* lb, int* lcur, int* s, int2* stage) {
  int t = threadIdx.x;

  // local exclusive scan of this chunk's bucket counts
  int v = (t < NB) ? cbc[c * NB + t] : 0;
  s[t] = v;
  __syncthreads();
#pragma unroll
  for (int d = 1; d < 256; d <<= 1) {
    int val = (t >= d) ? s[t - d] : 0;
    __syncthreads();
    s[t] += val;
    __syncthreads();
  }
  if (t < NB) {
    int excl = s[t] - v;
    lb[t] = excl;
    lcur[t] = excl;
  }
  if (t == 255) lb[NB] = s[255];  // edges in this chunk
  __syncthreads();

  // scatter into LDS (bucket-grouped)
#pragma unroll
  for (int k = 0; k < EPB / 256; ++k) {
    int e = c * EPB + k * 256 + t;
    if (e < N_EDGES) {
      int src = ei[e];
      int d = ei[N_EDGES + e];
      int p = atomicAdd(&lcur[d >> BSHIFT], 1);
      stage[p] = make_int2(src, d);
    }
  }
  __syncthreads();

  // coalesced flush: wave w handles buckets w, w+4, ...
  int wv = t >> 6, lane = t & 63;
  for (int b = wv; b < NB; b += 4) {
    int l0 = lb[b], l1 = lb[b + 1];
    int gb = bbase[b] + cpre[c * NB + b];
    for (int i = lane; i < l1 - l0; i += 64) ebuf[gb + i] = stage[l0 + i];
  }
}

// ---------- MERGED front-end #1: swizzle_w || bucket_count || gbound ------
__global__ __launch_bounds__(256)
void front1(const float* __restrict__ W0, const float* __restrict__ W1,
            const float* __restrict__ W2, half8* __restrict__ Wswz,
            const int* __restrict__ ei, int* __restrict__ cbc,
            const int* __restrict__ batch, int* __restrict__ goff) {
  int bid = blockIdx.x;
  int t = threadIdx.x;
  if (bid < SWZ_BLOCKS) {
    // ---- W swizzle: f32 [128][128] -> fp16 B-fragment order (m89) ----
    int f = bid * 256 + t;            // 0..6143
    int which = f >> 11;
    const float* W = (which == 0) ? W0 : ((which == 1) ? W1 : W2);
    int r = f & 2047;
    int frag = r >> 6;                // k0*8+nt
    int lane = r & 63;
    int k0 = frag >> 3, nt = frag & 7;
    int n = nt * 16 + (lane & 15);
    int kbase = k0 * 32 + (lane >> 4) * 8;
    half8 hb;
#pragma unroll
    for (int j = 0; j < 8; ++j) hb[j] = (_Float16)W[(kbase + j) * 128 + n];
    Wswz[f] = hb;
  } else if (bid < SWZ_BLOCKS + NCHUNKS) {
    // ---- per-chunk histogram over 196 buckets ----
    __shared__ int hist[NB];
    int c = bid - SWZ_BLOCKS;
    if (t < NB) hist[t] = 0;
    __syncthreads();
#pragma unroll
    for (int k = 0; k < EPB / 256; ++k) {
      int e = c * EPB + k * 256 + t;
      if (e < N_EDGES) atomicAdd(&hist[ei[N_EDGES + e] >> BSHIFT], 1);
    }
    __syncthreads();
    if (t < NB) cbc[c * NB + t] = hist[t];
  } else {
    // ---- graph (pooling) ranges from SORTED batch ----
    int i = (bid - SWZ_BLOCKS - NCHUNKS) * 256 + t;
    if (i >= N_NODES) return;
    int b = batch[i];
    if (i == 0) {
      for (int g = 0; g <= b; ++g) goff[g] = 0;
    } else {
      int a = batch[i - 1];
      for (int g = a + 1; g <= b; ++g) goff[g] = i;
    }
    if (i == N_NODES - 1) {
      for (int g = b + 1; g <= NGRAPH; ++g) goff[g] = N_NODES;
    }
  }
}

// ---------- MERGED mid: layer-0 GEMM (fp32 A) || bucket_scatter -----------
// R1's proven pairing: 1173 blocks, union'd LDS, true overlap.
__global__ __launch_bounds__(256)
void mid2(const float* __restrict__ x, const half8* __restrict__ Wswz,
          __half* __restrict__ hbuf,
          const int* __restrict__ ei, const int* __restrict__ cbc,
          const int* __restrict__ cpre, const int* __restrict__ bbase,
          int2* __restrict__ ebuf) {
  __shared__ union {
    half8 WtF[2048];                                    // 32 KB (gemm path)
    struct { int lb[NB + 1]; int lcur[NB]; int s[256]; int2 stage[EPB]; } sc;
  } u;
  int bid = blockIdx.x;
  if (bid < GEMM_BLOCKS) {
    gemm_mfma_body<false, false>(x, Wswz, hbuf, N_NODES, u.WtF, bid, nullptr);
  } else {
    scatter_body(ei, cbc, cpre, bbase, ebuf, bid - GEMM_BLOCKS,
                 u.sc.lb, u.sc.lcur, u.sc.s, u.sc.stage);
  }
}

// B1: per-bucket exclusive scan along the chunk axis (parallel over buckets)
__global__ __launch_bounds__(256)
void scan_chunks(const int* __restrict__ cbc, int* __restrict__ cpre,
                 int* __restrict__ btot) {
  __shared__ int s[256];
  int b = blockIdx.x;
  int t = threadIdx.x;
  int c0 = 2 * t, c1 = 2 * t + 1;
  int v0 = (c0 < NCHUNKS) ? cbc[c0 * NB + b] : 0;
  int v1 = (c1 < NCHUNKS) ? cbc[c1 * NB + b] : 0;
  int sum = v0 + v1;
  s[t] = sum;
  __syncthreads();
#pragma unroll
  for (int d = 1; d < 256; d <<= 1) {
    int val = (t >= d) ? s[t - d] : 0;
    __syncthreads();
    s[t] += val;
    __syncthreads();
  }
  int run = s[t] - sum;
  if (c0 < NCHUNKS) cpre[c0 * NB + b] = run;
  if (c1 < NCHUNKS) cpre[c1 * NB + b] = run + v0;
  if (t == 255) btot[b] = s[255];
}

// B2: exclusive scan over bucket totals -> bbase[b], bbase[NB] = E
__global__ __launch_bounds__(256)
void scan_base(const int* __restrict__ btot, int* __restrict__ bbase) {
  __shared__ int s[256];
  int t = threadIdx.x;
  int v = (t < NB) ? btot[t] : 0;
  s[t] = v;
  __syncthreads();
#pragma unroll
  for (int d = 1; d < 256; d <<= 1) {
    int val = (t >= d) ? s[t - d] : 0;
    __syncthreads();
    s[t] += val;
    __syncthreads();
  }
  if (t < NB) bbase[t] = s[t] - v;
  if (t == 255) bbase[NB] = s[255];  // == N_EDGES
}

// D: one block per bucket: LDS 512-histogram + local scan -> off, dinv,
// and dst-sorted csrc.
__global__ __launch_bounds__(256)
void bucket_csr(const int2* __restrict__ ebuf, const int* __restrict__ bbase,
                int* __restrict__ off, float* __restrict__ dinv,
                int* __restrict__ csrc) {
  __shared__ int hist[BUCKW];
  __shared__ int cur[BUCKW];
  __shared__ int s[256];
  int t = threadIdx.x;
  int b = blockIdx.x;
  int node0 = b << BSHIFT;
  int ebeg = bbase[b], eend = bbase[b + 1];

  hist[t] = 0; hist[t + 256] = 0;
  __syncthreads();
  for (int e = ebeg + t; e < eend; e += 256)
    atomicAdd(&hist[ebuf[e].y - node0], 1);
  __syncthreads();

  int a = hist[2 * t], bq = hist[2 * t + 1];
  int sum = a + bq;
  s[t] = sum;
  __syncthreads();
#pragma unroll
  for (int d = 1; d < 256; d <<= 1) {
    int val = (t >= d) ? s[t - d] : 0;
    __syncthreads();
    s[t] += val;
    __syncthreads();
  }
  int run = s[t] - sum;
  cur[2 * t] = run;
  cur[2 * t + 1] = run + a;

  int i0 = node0 + 2 * t, i1 = node0 + 2 * t + 1;
  if (i0 < N_NODES) {
    off[i0] = ebeg + run;
    dinv[i0] = rsqrtf((float)(a + 1));
  }
  if (i1 < N_NODES) {
    off[i1] = ebeg + run + a;
    dinv[i1] = rsqrtf((float)(bq + 1));
  }
  if (b == NB - 1 && t == 0) off[N_NODES] = N_EDGES;
  __syncthreads();

  for (int e = ebeg + t; e < eend; e += 256) {
    int2 ed = ebuf[e];
    int p = atomicAdd(&cur[ed.y - node0], 1);
    csrc[ebeg + p] = ed.x;
  }
}

// ---------- aggregation (R1's proven wave/node scalar-path shape) ---------
// R16: template<PRE>. PRE consumes prescaled h' = dinv*H (from the GEMM
// epilogue): inner loop is csrc -> h2 -> add, with NO dependent dinv[s]
// scalar loads and no per-edge fma weight. NONPRE = R1's exact form
// (layer 0, whose GEMM runs before dinv exists).
template <bool PRE>
__global__ __launch_bounds__(256)
void aggregate(const __half* __restrict__ h, const int* __restrict__ off,
               const int* __restrict__ csrc, const float* __restrict__ dinv,
               const float* __restrict__ bias, __half* __restrict__ out) {
  int gid = blockIdx.x * blockDim.x + threadIdx.x;
  int node = __builtin_amdgcn_readfirstlane(gid >> 6);   // wave-uniform
  int lane = threadIdx.x & 63;
  if (node >= N_NODES) return;
  const __half2* h2 = (const __half2*)h;

  int beg = off[node], end = off[node + 1];
  float a0 = 0.f, a1 = 0.f;
  float b0_ = 0.f, b1_ = 0.f;
  float c0 = 0.f, c1 = 0.f;
  float d0 = 0.f, d1 = 0.f;

  int e = beg;
  for (; e + 8 <= end; e += 8) {
    int s0 = csrc[e + 0], s1 = csrc[e + 1], s2 = csrc[e + 2], s3 = csrc[e + 3];
    int s4 = csrc[e + 4], s5 = csrc[e + 5], s6 = csrc[e + 6], s7 = csrc[e + 7];
    float2 f0 = __half22float2(h2[(size_t)s0 * 64 + lane]);
    float2 f1 = __half22float2(h2[(size_t)s1 * 64 + lane]);
    float2 f2 = __half22float2(h2[(size_t)s2 * 64 + lane]);
    float2 f3 = __half22float2(h2[(size_t)s3 * 64 + lane]);
    float2 f4 = __half22float2(h2[(size_t)s4 * 64 + lane]);
    float2 f5 = __half22float2(h2[(size_t)s5 * 64 + lane]);
    float2 f6 = __half22float2(h2[(size_t)s6 * 64 + lane]);
    float2 f7 = __half22float2(h2[(size_t)s7 * 64 + lane]);
    if constexpr (PRE) {
      a0 += f0.x; a1 += f0.y;  b0_ += f1.x; b1_ += f1.y;
      c0 += f2.x; c1 += f2.y;  d0 += f3.x; d1 += f3.y;
      a0 += f4.x; a1 += f4.y;  b0_ += f5.x; b1_ += f5.y;
      c0 += f6.x; c1 += f6.y;  d0 += f7.x; d1 += f7.y;
    } else {
      float w0 = dinv[s0], w1 = dinv[s1], w2 = dinv[s2], w3 = dinv[s3];
      float w4 = dinv[s4], w5 = dinv[s5], w6 = dinv[s6], w7 = dinv[s7];
      a0 = fmaf(w0, f0.x, a0); a1 = fmaf(w0, f0.y, a1);
      b0_ = fmaf(w1, f1.x, b0_); b1_ = fmaf(w1, f1.y, b1_);
      c0 = fmaf(w2, f2.x, c0); c1 = fmaf(w2, f2.y, c1);
      d0 = fmaf(w3, f3.x, d0); d1 = fmaf(w3, f3.y, d1);
      a0 = fmaf(w4, f4.x, a0); a1 = fmaf(w4, f4.y, a1);
      b0_ = fmaf(w5, f5.x, b0_); b1_ = fmaf(w5, f5.y, b1_);
      c0 = fmaf(w6, f6.x, c0); c1 = fmaf(w6, f6.y, c1);
      d0 = fmaf(w7, f7.x, d0); d1 = fmaf(w7, f7.y, d1);
    }
  }
  if (e + 4 <= end) {
    int s0 = csrc[e + 0], s1 = csrc[e + 1], s2 = csrc[e + 2], s3 = csrc[e + 3];
    float2 f0 = __half22float2(h2[(size_t)s0 * 64 + lane]);
    float2 f1 = __half22float2(h2[(size_t)s1 * 64 + lane]);
    float2 f2 = __half22float2(h2[(size_t)s2 * 64 + lane]);
    float2 f3 = __half22float2(h2[(size_t)s3 * 64 + lane]);
    if constexpr (PRE) {
      a0 += f0.x; a1 += f0.y;  b0_ += f1.x; b1_ += f1.y;
      c0 += f2.x; c1 += f2.y;  d0 += f3.x; d1 += f3.y;
    } else {
      float w0 = dinv[s0], w1 = dinv[s1], w2 = dinv[s2], w3 = dinv[s3];
      a0 = fmaf(w0, f0.x, a0); a1 = fmaf(w0, f0.y, a1);
      b0_ = fmaf(w1, f1.x, b0_); b1_ = fmaf(w1, f1.y, b1_);
      c0 = fmaf(w2, f2.x, c0); c1 = fmaf(w2, f2.y, c1);
      d0 = fmaf(w3, f3.x, d0); d1 = fmaf(w3, f3.y, d1);
    }
    e += 4;
  }
  if (e + 2 <= end) {
    int s0 = csrc[e + 0], s1 = csrc[e + 1];
    float2 f0 = __half22float2(h2[(size_t)s0 * 64 + lane]);
    float2 f1 = __half22float2(h2[(size_t)s1 * 64 + lane]);
    if constexpr (PRE) {
      a0 += f0.x; a1 += f0.y;  b0_ += f1.x; b1_ += f1.y;
    } else {
      float w0 = dinv[s0], w1 = dinv[s1];
      a0 = fmaf(w0, f0.x, a0); a1 = fmaf(w0, f0.y, a1);
      b0_ = fmaf(w1, f1.x, b0_); b1_ = fmaf(w1, f1.y, b1_);
    }
    e += 2;
  }
  if (e < end) {
    int s0 = csrc[e];
    float2 f0 = __half22float2(h2[(size_t)s0 * 64 + lane]);
    if constexpr (PRE) {
      a0 += f0.x; a1 += f0.y;
    } else {
      float w0 = dinv[s0];
      a0 = fmaf(w0, f0.x, a0); a1 = fmaf(w0, f0.y, a1);
    }
  }

  float dv = dinv[node];
  float2 vs = __half22float2(h2[(size_t)node * 64 + lane]);
  float s0f, s1f;
  if constexpr (PRE) {
    // vs is already h' = dinv*H; self term dinv^2*H = dinv*h'
    s0f = ((a0 + b0_) + (c0 + d0) + vs.x) * dv;
    s1f = ((a1 + b1_) + (c1 + d1) + vs.y) * dv;
  } else {
    s0f = ((a0 + b0_) + (c0 + d0) + dv * vs.x) * dv;
    s1f = ((a1 + b1_) + (c1 + d1) + dv * vs.y) * dv;
  }

  float2 bb = ((const float2*)bias)[lane];
  float ox = elu1(s0f + bb.x);
  float oy = elu1(s1f + bb.y);
  ((__half2*)out)[(size_t)node * 64 + lane] = __floats2half2_rn(ox, oy);
}

// ---------- fused max-pool + linear head + softmax ----------
// R16: half2 feature reads (4 row-streams x 64 lanes x 4B vs 2 x 128 x 2B)
__global__ __launch_bounds__(256)
void pool_head(const __half* __restrict__ feat, const int* __restrict__ goff,
               const float* __restrict__ Wl, const float* __restrict__ bl,
               float* __restrict__ out) {
  int g = blockIdx.x;
  int t = threadIdx.x;          // 0..255
  int fp = t & 63;              // feature pair (2fp, 2fp+1)
  int r = t >> 6;               // row stream 0..3
  int beg = goff[g], end = goff[g + 1];
  const __half2* f2 = (const __half2*)feat;   // row stride 64

  float m0x = -INFINITY, m0y = -INFINITY, m1x = -INFINITY, m1y = -INFINITY;
  int i = beg + r;
  for (; i + 4 < end; i += 8) {
    float2 u = __half22float2(f2[(size_t)i * 64 + fp]);
    float2 v = __half22float2(f2[(size_t)(i + 4) * 64 + fp]);
    m0x = fmaxf(m0x, u.x); m0y = fmaxf(m0y, u.y);
    m1x = fmaxf(m1x, v.x); m1y = fmaxf(m1y, v.y);
  }
  for (; i < end; i += 4) {
    float2 u = __half22float2(f2[(size_t)i * 64 + fp]);
    m0x = fmaxf(m0x, u.x); m0y = fmaxf(m0y, u.y);
  }
  m0x = fmaxf(m0x, m1x); m0y = fmaxf(m0y, m1y);

  __shared__ float pl[4][HDIM];
  __shared__ float red[HDIM];
  __shared__ float lg[NCLS];
  pl[r][2 * fp] = m0x;
  pl[r][2 * fp + 1] = m0y;
  __syncthreads();

  if (t < HDIM) {
    float mm = fmaxf(fmaxf(pl[0][t], pl[1][t]), fmaxf(pl[2][t], pl[3][t]));
    if (beg == end) mm = 0.f;
    red[t] = mm;
  }
  __syncthreads();

  if (t < NCLS) {
    float acc = bl[t];
#pragma unroll
    for (int ff = 0; ff < HDIM; ++ff) acc = fmaf(red[ff], Wl[ff * NCLS + t], acc);
    lg[t] = acc;
  }
  __syncthreads();

  if (t < NCLS) {
    float mx = lg[0];
#pragma unroll
    for (int c = 1; c < NCLS; ++c) mx = fmaxf(mx, lg[c]);
    float ssum = 0.f;
#pragma unroll
    for (int c = 0; c < NCLS; ++c) ssum += __expf(lg[c] - mx);
    out[g * NCLS + t] = __expf(lg[t] - mx) / ssum;
  }
}

// ---------- launch ----------

extern "C" void kernel_launch(void* const* d_in, const int* in_sizes, int n_in,
                              void* d_out, int out_size, void* d_ws, size_t ws_size,
                              hipStream_t stream) {
  const float* x    = (const float*)d_in[0];
  const int*   ei   = (const int*)d_in[1];
  const int*   batch= (const int*)d_in[2];
  const float* W0 = (const float*)d_in[3]; const float* b0 = (const float*)d_in[4];
  const float* W1 = (const float*)d_in[5]; const float* b1 = (const float*)d_in[6];
  const float* W2 = (const float*)d_in[7]; const float* b2 = (const float*)d_in[8];
  const float* Wl = (const float*)d_in[9]; const float* bl = (const float*)d_in[10];
  float* out = (float*)d_out;

  char* w = (char*)d_ws;
  auto alloc = [&](size_t bytes) {
    char* p = w;
    w += (bytes + 255) & ~(size_t)255;
    return p;
  };
  int*    cbc    = (int*)   alloc((size_t)NCHUNKS * NB * 4);
  int*    cpre   = (int*)   alloc((size_t)NCHUNKS * NB * 4);
  int*    btot   = (int*)   alloc((size_t)NB * 4);
  int*    bbase  = (int*)   alloc((size_t)(NB + 1) * 4);
  int2*   ebuf   = (int2*)  alloc((size_t)N_EDGES * 8);
  int*    off    = (int*)   alloc((size_t)(N_NODES + 1) * 4);
  float*  dinv   = (float*) alloc((size_t)N_NODES * 4);
  int*    goff   = (int*)   alloc((size_t)(NGRAPH + 1) * 4);
  int*    csrc   = (int*)   alloc((size_t)N_EDGES * 4);
  half8*  Wswz   = (half8*) alloc((size_t)3 * 2048 * 16);
  __half* hbufA  = (__half*)alloc((size_t)N_NODES * HDIM * 2);
  __half* feat   = (__half*)alloc((size_t)N_NODES * HDIM * 2);

  // merged front-end: W swizzle || per-chunk bucket histogram || graph bounds
  front1<<<SWZ_BLOCKS + NCHUNKS + GB_BLOCKS, 256, 0, stream>>>(
      W0, W1, W2, Wswz, ei, cbc, batch, goff);

  // scan chain (dependent, tiny)
  scan_chunks<<<NB, 256, 0, stream>>>(cbc, cpre, btot);
  scan_base<<<1, 256, 0, stream>>>(btot, bbase);

  // layer-0 GEMM runs concurrently with the edge scatter
  mid2<<<GEMM_BLOCKS + NCHUNKS, 256, 0, stream>>>(
      x, Wswz, hbufA, ei, cbc, cpre, bbase, ebuf);

  bucket_csr<<<NB, 256, 0, stream>>>(ebuf, bbase, off, dinv, csrc);

  const int AGG_BLOCKS = ((size_t)N_NODES * 64 + 255) / 256;   // 25000

  // layer 1: NONPRE (gemm0 ran before dinv existed)
  aggregate<false><<<AGG_BLOCKS, 256, 0, stream>>>(
      hbufA, off, csrc, dinv, b0, feat);

  // layers 2,3: GEMM epilogue prescales -> PRE aggregate (no dinv chain)
  gemm_mfma_h<<<GEMM_BLOCKS, 256, 0, stream>>>(feat, Wswz + 2048, hbufA,
                                               N_NODES, dinv);
  aggregate<true><<<AGG_BLOCKS, 256, 0, stream>>>(
      hbufA, off, csrc, dinv, b1, feat);

  gemm_mfma_h<<<GEMM_BLOCKS, 256, 0, stream>>>(feat, Wswz + 4096, hbufA,
                                               N_NODES, dinv);
  aggregate<true><<<AGG_BLOCKS, 256, 0, stream>>>(
      hbufA, off, csrc, dinv, b2, feat);

  pool_head<<<NGRAPH, 256, 0, stream>>>(feat, goff, Wl, bl, out);
}